// Round 1
// baseline (190.330 us; speedup 1.0000x reference)
//
#include <hip/hip_runtime.h>
#include <hip/hip_bf16.h>
#include <math.h>

typedef __attribute__((ext_vector_type(8))) short short8;   // bf16x8 MFMA frag
typedef __attribute__((ext_vector_type(4))) float floatx4;  // f32x4 MFMA acc

static __device__ __forceinline__ unsigned short f2bf(float x) {
    union { float f; unsigned u; } v; v.f = x;
    unsigned r = v.u + 0x7FFFu + ((v.u >> 16) & 1u);
    return (unsigned short)(r >> 16);
}

// ---------------- Kernel 1: QKV projections ----------------
// out[o][n] = sum_c W[o][c] * feat[b][c][n] + bias[o]
// proj 0 -> Qt[b][n][o] bf16 ; proj 1 -> Kt[b][n][o] bf16 ; proj 2 -> V[b][o][n] bf16
__global__ __launch_bounds__(256) void qkv_kernel(
    const float* __restrict__ feat,
    const float* __restrict__ Wq, const float* __restrict__ bq,
    const float* __restrict__ Wk, const float* __restrict__ bk,
    const float* __restrict__ Wv, const float* __restrict__ bv,
    unsigned short* __restrict__ Qt, unsigned short* __restrict__ Kt,
    unsigned short* __restrict__ Vb, int N)
{
    const int nb = blockIdx.x * 64;
    const int proj = blockIdx.y;
    const int b = blockIdx.z;
    const float* W    = proj == 0 ? Wq : (proj == 1 ? Wk : Wv);
    const float* bias = proj == 0 ? bq : (proj == 1 ? bk : bv);
    const int t = threadIdx.x;
    const int n_l = t & 63, og = t >> 6;

    __shared__ float feat_s[8][64];
    __shared__ float W_s[8][128];

    float acc[32];
#pragma unroll
    for (int i = 0; i < 32; ++i) acc[i] = 0.f;

    const float* fbase = feat + (size_t)b * 128 * N + nb;

    for (int cb = 0; cb < 16; ++cb) {
        { // stage feat tile 8x64
            int f = t * 2;
            int cc = f >> 6, nn = f & 63;
            float2 v = *(const float2*)(fbase + (size_t)(cb * 8 + cc) * N + nn);
            feat_s[cc][nn] = v.x; feat_s[cc][nn + 1] = v.y;
        }
        { // stage W tile transposed: W_s[cc][o] = W[o][cb*8+cc]
            int o = t >> 1, cc0 = (t & 1) * 4;
            float4 w = *(const float4*)(W + o * 128 + cb * 8 + cc0);
            W_s[cc0 + 0][o] = w.x; W_s[cc0 + 1][o] = w.y;
            W_s[cc0 + 2][o] = w.z; W_s[cc0 + 3][o] = w.w;
        }
        __syncthreads();
#pragma unroll
        for (int cc = 0; cc < 8; ++cc) {
            float f = feat_s[cc][n_l];
            const float4* wrow = (const float4*)&W_s[cc][og * 32];
#pragma unroll
            for (int j = 0; j < 8; ++j) {
                float4 w = wrow[j];
                acc[j * 4 + 0] += w.x * f; acc[j * 4 + 1] += w.y * f;
                acc[j * 4 + 2] += w.z * f; acc[j * 4 + 3] += w.w * f;
            }
        }
        __syncthreads();
    }

    if (proj < 2) {
        unsigned short* T = (proj == 0 ? Qt : Kt) + (size_t)b * N * 128
                          + (size_t)(nb + n_l) * 128 + og * 32;
#pragma unroll
        for (int q4 = 0; q4 < 4; ++q4) {
            unsigned uu[4];
#pragma unroll
            for (int j = 0; j < 4; ++j) {
                int idx = q4 * 8 + j * 2;
                unsigned short l0 = f2bf(acc[idx]     + bias[og * 32 + idx]);
                unsigned short h0 = f2bf(acc[idx + 1] + bias[og * 32 + idx + 1]);
                uu[j] = (unsigned)l0 | ((unsigned)h0 << 16);
            }
            ((uint4*)T)[q4] = make_uint4(uu[0], uu[1], uu[2], uu[3]);
        }
    } else {
        unsigned short* T = Vb + (size_t)b * 128 * N;
#pragma unroll
        for (int oi = 0; oi < 32; ++oi) {
            int o = og * 32 + oi;
            T[(size_t)o * N + nb + n_l] = f2bf(acc[oi] + bias[o]);
        }
    }
}

// ---------------- Kernel 2: fused flash attention ----------------
// Per block: 32 output positions (o), loop i in tiles of 128, 8 waves.
// S^T = K^T Q via mfma (A=Kt rows, B=Qt rows), online softmax, P via LDS, PV via mfma.
#define PS 136   // P_s row stride (bf16)
#define AS 132   // att_s row stride (f32)
__global__ __launch_bounds__(512) void attn_kernel(
    const unsigned short* __restrict__ Qt, const unsigned short* __restrict__ Kt,
    const unsigned short* __restrict__ Vb, const float* __restrict__ att,
    float* __restrict__ msg, int N)
{
    const int b = blockIdx.y;
    const int obase = blockIdx.x * 32;
    const int t = threadIdx.x;
    const int w = t >> 6, lane = t & 63, g = lane >> 4, q = lane & 15;

    __shared__ float att_s[32 * AS];
    __shared__ unsigned short P_s[32 * PS];
    __shared__ float wavemax[8 * 32], wavesum[8 * 32];
    __shared__ float m_s[32], l_s[32];

    const unsigned short* Qb  = Qt + (size_t)b * N * 128;
    const unsigned short* Kb  = Kt + (size_t)b * N * 128;
    const unsigned short* Vbp = Vb + (size_t)b * 128 * N;
    const float* attb = att + (size_t)b * N * N;

    // preload Q fragments (B-operand): qf[ot][cs]
    short8 qf[2][4];
#pragma unroll
    for (int ot = 0; ot < 2; ++ot)
#pragma unroll
        for (int cs = 0; cs < 4; ++cs)
            qf[ot][cs] = *(const short8*)(Qb + (size_t)(obase + 16 * ot + q) * 128 + cs * 32 + g * 8);

    floatx4 macc[2] = {{0.f,0.f,0.f,0.f},{0.f,0.f,0.f,0.f}};
    if (t < 32) { m_s[t] = -INFINITY; l_s[t] = 0.f; }

    const float rsd = 0.08838834764831845f;  // 1/sqrt(128)
    const int ntiles = N / 128;

    for (int it = 0; it < ntiles; ++it) {
        const int ibase = it * 128;
        { // stage att tile [32][128]
            int f0 = t * 8;
            int o = f0 >> 7, i = f0 & 127;
            const float* src = attb + (size_t)(obase + o) * N + ibase + i;
            float4 v0 = ((const float4*)src)[0];
            float4 v1 = ((const float4*)src)[1];
            *(float4*)&att_s[o * AS + i]     = v0;
            *(float4*)&att_s[o * AS + i + 4] = v1;
        }
        // S^T fragments: rows i = 16w + g*4 + r, cols o = 16*ot + q
        floatx4 sacc[2] = {{0.f,0.f,0.f,0.f},{0.f,0.f,0.f,0.f}};
#pragma unroll
        for (int cs = 0; cs < 4; ++cs) {
            short8 kf = *(const short8*)(Kb + (size_t)(ibase + 16 * w + q) * 128 + cs * 32 + g * 8);
            sacc[0] = __builtin_amdgcn_mfma_f32_16x16x32_bf16(kf, qf[0][cs], sacc[0], 0, 0, 0);
            sacc[1] = __builtin_amdgcn_mfma_f32_16x16x32_bf16(kf, qf[1][cs], sacc[1], 0, 0, 0);
        }
        __syncthreads();  // att_s ready; prev P_s consumed; prev m_s/l_s written

        float sv[2][4], pm[2];
#pragma unroll
        for (int ot = 0; ot < 2; ++ot) {
            int o = 16 * ot + q;
#pragma unroll
            for (int r = 0; r < 4; ++r) {
                int i = 16 * w + g * 4 + r;
                sv[ot][r] = sacc[ot][r] * rsd * att_s[o * AS + i];
            }
            pm[ot] = fmaxf(fmaxf(sv[ot][0], sv[ot][1]), fmaxf(sv[ot][2], sv[ot][3]));
        }
#pragma unroll
        for (int off = 16; off < 64; off <<= 1) {
            pm[0] = fmaxf(pm[0], __shfl_xor(pm[0], off));
            pm[1] = fmaxf(pm[1], __shfl_xor(pm[1], off));
        }
        if (g == 0) { wavemax[w * 32 + q] = pm[0]; wavemax[w * 32 + 16 + q] = pm[1]; }
        __syncthreads();  // wavemax ready

        float mnew[2], scale[2], psum[2];
#pragma unroll
        for (int ot = 0; ot < 2; ++ot) {
            int o = 16 * ot + q;
            float mo = m_s[o];
            float tm = wavemax[o];
#pragma unroll
            for (int w2 = 1; w2 < 8; ++w2) tm = fmaxf(tm, wavemax[w2 * 32 + o]);
            float mn = fmaxf(mo, tm);
            mnew[ot] = mn;
            scale[ot] = __expf(mo - mn);
            float ps = 0.f;
#pragma unroll
            for (int r = 0; r < 4; ++r) {
                float p = __expf(sv[ot][r] - mn);
                sv[ot][r] = p; ps += p;
            }
            psum[ot] = ps;
            macc[ot] *= scale[ot];
        }
#pragma unroll
        for (int off = 16; off < 64; off <<= 1) {
            psum[0] += __shfl_xor(psum[0], off);
            psum[1] += __shfl_xor(psum[1], off);
        }
        if (g == 0) { wavesum[w * 32 + q] = psum[0]; wavesum[w * 32 + 16 + q] = psum[1]; }
#pragma unroll
        for (int ot = 0; ot < 2; ++ot) {
            int o = 16 * ot + q;
#pragma unroll
            for (int r = 0; r < 4; ++r)
                P_s[o * PS + 16 * w + g * 4 + r] = f2bf(sv[ot][r]);
        }
        __syncthreads();  // P_s + wavesum ready

        if (t < 16) {  // wave0 g==0 lanes: q==t, scale[]/mnew[] correspond to o=16*ot+t
#pragma unroll
            for (int ot = 0; ot < 2; ++ot) {
                int o = 16 * ot + t;
                float ts = wavesum[o];
#pragma unroll
                for (int w2 = 1; w2 < 8; ++w2) ts += wavesum[w2 * 32 + o];
                l_s[o] = l_s[o] * scale[ot] + ts;
                m_s[o] = mnew[ot];
            }
        }
        // PV: A = V rows c in [16w,16w+16), k = i ; B = P^T from LDS
#pragma unroll
        for (int ks = 0; ks < 4; ++ks) {
            short8 vf  = *(const short8*)(Vbp + (size_t)(16 * w + q) * N + ibase + ks * 32 + g * 8);
            short8 pf0 = *(const short8*)&P_s[q * PS + ks * 32 + g * 8];
            short8 pf1 = *(const short8*)&P_s[(16 + q) * PS + ks * 32 + g * 8];
            macc[0] = __builtin_amdgcn_mfma_f32_16x16x32_bf16(vf, pf0, macc[0], 0, 0, 0);
            macc[1] = __builtin_amdgcn_mfma_f32_16x16x32_bf16(vf, pf1, macc[1], 0, 0, 0);
        }
    }
    __syncthreads();
#pragma unroll
    for (int ot = 0; ot < 2; ++ot) {
        int o = 16 * ot + q;
        float linv = 1.f / l_s[o];
#pragma unroll
        for (int r = 0; r < 4; ++r) {
            int c = 16 * w + g * 4 + r;
            msg[(size_t)(b * 128 + c) * N + obase + o] = macc[ot][r] * linv;
        }
    }
}

// ---------------- Kernel 3: fused MLP + residual ----------------
__global__ __launch_bounds__(256) void mlp_kernel(
    const float* __restrict__ msg, const float* __restrict__ feat,
    const float* __restrict__ W1, const float* __restrict__ b1,
    const float* __restrict__ g1, const float* __restrict__ be1,
    const float* __restrict__ m1, const float* __restrict__ v1,
    const float* __restrict__ W2, const float* __restrict__ b2,
    const float* __restrict__ g2, const float* __restrict__ be2,
    const float* __restrict__ m2, const float* __restrict__ v2,
    const float* __restrict__ W3, const float* __restrict__ b3,
    float* __restrict__ out, int N)
{
    const int b = blockIdx.y;
    const int nb = blockIdx.x * 64;
    const int t = threadIdx.x;
    const int n_l = t & 63, og = t >> 6;
    const float EPS = 1e-5f;

    __shared__ float h1_s[64][64];
    __shared__ float h2_s[64][64];

    const float* msgb = msg + (size_t)b * 128 * N + nb;

    // phase 1: h1 (64 ch), og handles 16
    float acc[16];
#pragma unroll
    for (int i = 0; i < 16; ++i) acc[i] = 0.f;
    for (int c4 = 0; c4 < 128; c4 += 4) {
        float f0 = msgb[(size_t)(c4 + 0) * N + n_l];
        float f1 = msgb[(size_t)(c4 + 1) * N + n_l];
        float f2 = msgb[(size_t)(c4 + 2) * N + n_l];
        float f3 = msgb[(size_t)(c4 + 3) * N + n_l];
#pragma unroll
        for (int oi = 0; oi < 16; ++oi) {
            float4 wv = *(const float4*)(W1 + (og * 16 + oi) * 128 + c4);
            acc[oi] += wv.x * f0 + wv.y * f1 + wv.z * f2 + wv.w * f3;
        }
    }
#pragma unroll
    for (int oi = 0; oi < 16; ++oi) {
        int o = og * 16 + oi;
        float inv = g1[o] / sqrtf(v1[o] + EPS);
        float val = (acc[oi] + b1[o]) * inv + (be1[o] - m1[o] * inv);
        h1_s[o][n_l] = fmaxf(val, 0.f);
    }
    __syncthreads();

    // phase 2: h2 (64 ch)
    float acc2[16];
#pragma unroll
    for (int i = 0; i < 16; ++i) acc2[i] = 0.f;
    for (int c4 = 0; c4 < 64; c4 += 4) {
        float f0 = h1_s[c4 + 0][n_l], f1 = h1_s[c4 + 1][n_l];
        float f2 = h1_s[c4 + 2][n_l], f3 = h1_s[c4 + 3][n_l];
#pragma unroll
        for (int oi = 0; oi < 16; ++oi) {
            float4 wv = *(const float4*)(W2 + (og * 16 + oi) * 64 + c4);
            acc2[oi] += wv.x * f0 + wv.y * f1 + wv.z * f2 + wv.w * f3;
        }
    }
#pragma unroll
    for (int oi = 0; oi < 16; ++oi) {
        int o = og * 16 + oi;
        float inv = g2[o] / sqrtf(v2[o] + EPS);
        float val = (acc2[oi] + b2[o]) * inv + (be2[o] - m2[o] * inv);
        h2_s[o][n_l] = fmaxf(val, 0.f);
    }
    __syncthreads();

    // phase 3: out (128 ch), og handles 32, + bias + residual
    float acc3[32];
#pragma unroll
    for (int i = 0; i < 32; ++i) acc3[i] = 0.f;
    for (int c4 = 0; c4 < 64; c4 += 4) {
        float f0 = h2_s[c4 + 0][n_l], f1 = h2_s[c4 + 1][n_l];
        float f2 = h2_s[c4 + 2][n_l], f3 = h2_s[c4 + 3][n_l];
#pragma unroll
        for (int oi = 0; oi < 32; ++oi) {
            float4 wv = *(const float4*)(W3 + (og * 32 + oi) * 64 + c4);
            acc3[oi] += wv.x * f0 + wv.y * f1 + wv.z * f2 + wv.w * f3;
        }
    }
#pragma unroll
    for (int oi = 0; oi < 32; ++oi) {
        int o = og * 32 + oi;
        size_t idx = (size_t)(b * 128 + o) * N + nb + n_l;
        out[idx] = feat[idx] + acc3[oi] + b3[o];
    }
}

extern "C" void kernel_launch(void* const* d_in, const int* in_sizes, int n_in,
                              void* d_out, int out_size, void* d_ws, size_t ws_size,
                              hipStream_t stream)
{
    const float* feat = (const float*)d_in[0];
    const float* att  = (const float*)d_in[1];
    const float* Wq = (const float*)d_in[2];  const float* bq = (const float*)d_in[3];
    const float* Wk = (const float*)d_in[4];  const float* bk = (const float*)d_in[5];
    const float* Wv = (const float*)d_in[6];  const float* bv = (const float*)d_in[7];
    const float* W1 = (const float*)d_in[8];  const float* b1 = (const float*)d_in[9];
    const float* g1 = (const float*)d_in[10]; const float* be1 = (const float*)d_in[11];
    const float* m1 = (const float*)d_in[12]; const float* v1 = (const float*)d_in[13];
    const float* W2 = (const float*)d_in[14]; const float* b2 = (const float*)d_in[15];
    const float* g2 = (const float*)d_in[16]; const float* be2 = (const float*)d_in[17];
    const float* m2 = (const float*)d_in[18]; const float* v2 = (const float*)d_in[19];
    const float* W3 = (const float*)d_in[20]; const float* b3 = (const float*)d_in[21];

    long long bsN = (long long)in_sizes[0] / 128;   // bs*N
    long long NN  = (long long)in_sizes[1];         // bs*N*N
    int N  = (int)(NN / bsN);
    int bs = (int)(bsN / N);

    char* ws = (char*)d_ws;
    unsigned short* Qt = (unsigned short*)ws;            // bs*N*128 bf16 (row n, col c)
    unsigned short* Kt = Qt + (size_t)bs * N * 128;      // bs*N*128 bf16
    unsigned short* Vb = Kt + (size_t)bs * N * 128;      // bs*128*N bf16 (row c, col n)
    float* msg = (float*)(Vb + (size_t)bs * N * 128);    // bs*128*N f32

    dim3 grid1(N / 64, 3, bs);
    qkv_kernel<<<grid1, 256, 0, stream>>>(feat, Wq, bq, Wk, bk, Wv, bv, Qt, Kt, Vb, N);

    dim3 grid2(N / 32, bs);
    attn_kernel<<<grid2, 512, 0, stream>>>(Qt, Kt, Vb, att, msg, N);

    dim3 grid3(N / 64, bs);
    mlp_kernel<<<grid3, 256, 0, stream>>>(msg, feat,
        W1, b1, g1, be1, m1, v1, W2, b2, g2, be2, m2, v2, W3, b3,
        (float*)d_out, N);
}